// Round 2
// baseline (169.061 us; speedup 1.0000x reference)
//
#include <hip/hip_runtime.h>
#include <math.h>

#define S_LEN 2048
#define NH 16
#define DH 128
#define INNER 2048   // NH*DH
#define NROWS 4096   // B*S

typedef __attribute__((ext_vector_type(8))) short bf16x8;
typedef __attribute__((ext_vector_type(4))) float f32x4;
typedef __attribute__((ext_vector_type(2))) unsigned int u32x2;

__device__ __forceinline__ short f2bf(float f) {
  union { float f; unsigned u; } v; v.f = f;
  unsigned r = (v.u + 0x7fffu + ((v.u >> 16) & 1u)) >> 16;
  return (short)(unsigned short)r;
}
__device__ __forceinline__ float bf2f(short s) {
  union { unsigned u; float f; } v; v.u = ((unsigned)(unsigned short)s) << 16;
  return v.f;
}
// pack two f32 -> two bf16 in one uint: 2 adds + 1 v_perm (round half-away)
__device__ __forceinline__ int pkbf(float lo, float hi) {
  union { float f; unsigned u; } x, y;
  x.f = lo; y.f = hi;
  return (int)__builtin_amdgcn_perm(y.u + 0x8000u, x.u + 0x8000u, 0x07060302u);
}
// async global->LDS DMA, 16B per lane; LDS dest = uniform base + lane*16
__device__ __forceinline__ void gl2lds(const short* g, short* l) {
  __builtin_amdgcn_global_load_lds(
      (const __attribute__((address_space(1))) unsigned int*)g,
      (__attribute__((address_space(3))) unsigned int*)l, 16, 0, 0);
}
// (reg <-> lane-bit5) transpose: a' = {a lo32, b lo32}, b' = {a hi32, b hi32}
__device__ __forceinline__ void pl32swap(int& a, int& b) {
  u32x2 r = __builtin_amdgcn_permlane32_swap((unsigned)a, (unsigned)b, false, false);
  a = (int)r.x; b = (int)r.y;
}
// (reg <-> lane-bit4) transpose
__device__ __forceinline__ void pl16swap(int& a, int& b) {
  u32x2 r = __builtin_amdgcn_permlane16_swap((unsigned)a, (unsigned)b, false, false);
  a = (int)r.x; b = (int)r.y;
}

// ---------------- fused prep ----------------
// grid 2304: [0,512) rope table csT[s][i]{cos,sin}; [512,1024) X fp32->bf16;
// [1024,1792) Wq/Wk/Wv transpose; [1792,2048) Wo transpose; [2048,2304) zero out
__global__ void k_prep(const float* __restrict__ X, const float* __restrict__ Wq,
                       const float* __restrict__ Wk, const float* __restrict__ Wv,
                       const float* __restrict__ Wo,
                       float* __restrict__ csT, short* __restrict__ Xbf,
                       short* __restrict__ WT, short* __restrict__ WoT,
                       float* __restrict__ outz) {
  const int bx = blockIdx.x, tid = threadIdx.x;
  if (bx < 512) {
    int idx = bx * 256 + tid;           // s*64 + i
    int i = idx & 63, s = idx >> 6;
    double invf = pow(10000.0, -(double)i / 64.0);
    float ang = (float)((double)s * invf);
    float sv, cv; sincosf(ang, &sv, &cv);
    csT[idx * 2] = cv; csT[idx * 2 + 1] = sv;
    return;
  }
  if (bx < 1024) {
    int idx = ((bx - 512) * 256 + tid) * 4;
    float4 xv = *(const float4*)&X[idx];
    short4 o; o.x = f2bf(xv.x); o.y = f2bf(xv.y); o.z = f2bf(xv.z); o.w = f2bf(xv.w);
    *(short4*)&Xbf[idx] = o;
    return;
  }
  if (bx >= 2048) {                     // zero d_out
    float4 z4 = make_float4(0.f, 0.f, 0.f, 0.f);
    ((float4*)outz)[(bx - 2048) * 512 + tid] = z4;
    ((float4*)outz)[(bx - 2048) * 512 + tid + 256] = z4;
    return;
  }
  __shared__ float tile[32][33];
  const float* src; short* dst; int R, C, c0, r0;
  if (bx < 1792) {
    int z = (bx - 1024) >> 8, t = (bx - 1024) & 255;
    src = (z == 0) ? Wq : ((z == 1) ? Wk : Wv);
    dst = WT + (size_t)z * INNER * 128; R = 128; C = INNER;
    c0 = (t & 63) * 32; r0 = (t >> 6) * 32;
  } else {
    int t = bx - 1792;
    src = Wo; dst = WoT; R = INNER; C = 128;
    c0 = (t & 3) * 32; r0 = (t >> 2) * 32;
  }
  int tx = tid & 31, ty = tid >> 5;     // 32 x 8
  #pragma unroll
  for (int dy = 0; dy < 32; dy += 8)
    tile[ty + dy][tx] = src[(size_t)(r0 + ty + dy) * C + c0 + tx];
  __syncthreads();
  #pragma unroll
  for (int dy = 0; dy < 32; dy += 8)
    dst[(size_t)(c0 + ty + dy) * R + r0 + tx] = f2bf(tile[tx][ty + dy]);
}

// ---------------- fused QKV projection + RoPE ----------------
// grid (16 n-tiles = one head, 32 m-tiles of 128). Q/K MFMA transposed
// (rows = d): RoPE pairs in-lane, packed b64 epilogue. Q carries
// qscale*log2(e) so attention scores emerge in log2 domain.
// Q [bh][s][d] plain; K [bh][s][d] chunk-XOR swz; V [bh][tile][d][64] swz.
__global__ __launch_bounds__(256, 2) void k_qkv(
    const short* __restrict__ Xbf, const short* __restrict__ WT,
    const float* __restrict__ csT,
    short* __restrict__ Qg, short* __restrict__ Kg, short* __restrict__ Vg) {
  __shared__ __attribute__((aligned(16))) short As[128 * 136];
  __shared__ __attribute__((aligned(16))) short Bs[128 * 136];
  const int tid = threadIdx.x;
  const int n0 = blockIdx.x * 128, m0 = blockIdx.y * 128;
  for (int e = tid; e < 2048; e += 256)
    *(int4*)&As[(e >> 4) * 136 + (e & 15) * 8] =
        *(const int4*)&Xbf[(size_t)(m0 + (e >> 4)) * 128 + (e & 15) * 8];
  const int wid = tid >> 6, lane = tid & 63;
  const int l16 = lane & 15, quad = lane >> 4;
  const int wm = (wid & 1) * 64, wn = (wid >> 1) * 64;
  const int hh = n0 >> 7;                       // this block's head
  const int bb = m0 >> 11, ss = m0 & 2047;      // batch, seq base
  const float qscale = 0.12751745f;             // (1/sqrt(128)) * log2(e)
  for (int z = 0; z < 3; ++z) {
    __syncthreads();
    const short* Wp = WT + (size_t)z * INNER * 128;
    for (int e = tid; e < 2048; e += 256)
      *(int4*)&Bs[(e >> 4) * 136 + (e & 15) * 8] =
          *(const int4*)&Wp[(size_t)(n0 + (e >> 4)) * 128 + (e & 15) * 8];
    __syncthreads();
    f32x4 acc[4][4] = {};
    #pragma unroll
    for (int ks = 0; ks < 4; ++ks) {
      bf16x8 ax[4], bw[4];
      #pragma unroll
      for (int j = 0; j < 4; ++j) {
        ax[j] = *(const bf16x8*)&As[(wm + j * 16 + l16) * 136 + ks * 32 + quad * 8];
        bw[j] = *(const bf16x8*)&Bs[(wn + j * 16 + l16) * 136 + ks * 32 + quad * 8];
      }
      if (z < 2) {   // D[d][s]: A = W (m=d), B = X (n=s)
        #pragma unroll
        for (int dt = 0; dt < 4; ++dt)
          #pragma unroll
          for (int st = 0; st < 4; ++st)
            acc[dt][st] = __builtin_amdgcn_mfma_f32_16x16x32_bf16(bw[dt], ax[st], acc[dt][st], 0, 0, 0);
      } else {       // D[s][d]: A = X (m=s), B = W (n=d)
        #pragma unroll
        for (int mt = 0; mt < 4; ++mt)
          #pragma unroll
          for (int nt = 0; nt < 4; ++nt)
            acc[mt][nt] = __builtin_amdgcn_mfma_f32_16x16x32_bf16(ax[mt], bw[nt], acc[mt][nt], 0, 0, 0);
      }
    }
    if (z < 2) {
      __syncthreads();                  // waves done reading Bs
      #pragma unroll
      for (int dt = 0; dt < 4; ++dt)
        #pragma unroll
        for (int st = 0; st < 4; ++st) {
          int d0 = wn + dt * 16 + quad * 4;     // multiple of 4
          int sl = wm + st * 16 + l16;
          int sg = ss + sl;
          float4 cs = *(const float4*)&csT[((size_t)sg * 64 + (d0 >> 1)) * 2];
          float x0 = acc[dt][st][0], x1 = acc[dt][st][1];
          float x2 = acc[dt][st][2], x3 = acc[dt][st][3];
          float r0 = x0 * cs.x - x1 * cs.y, r1 = x1 * cs.x + x0 * cs.y;
          float r2 = x2 * cs.z - x3 * cs.w, r3 = x3 * cs.z + x2 * cs.w;
          if (z == 0) { r0 *= qscale; r1 *= qscale; r2 *= qscale; r3 *= qscale; }
          int2 pk; pk.x = pkbf(r0, r1); pk.y = pkbf(r2, r3);
          *(int2*)&Bs[sl * 136 + d0] = pk;
        }
      __syncthreads();
      short* dst = (z == 0 ? Qg : Kg) + (((size_t)(bb * NH + hh)) * S_LEN + ss) * DH;
      #pragma unroll
      for (int it = 0; it < 8; ++it) {
        int u = tid + 256 * it;                   // 2048 int4 units
        int row = u >> 4, c = u & 15;
        int cc = (z == 0) ? c : (c ^ (row & 15)); // K: chunk swizzle
        *(int4*)&dst[(size_t)row * DH + cc * 8] = *(const int4*)&Bs[row * 136 + c * 8];
      }
    } else {
      // V: transpose through As (dead now), tiled+swizzled [bh][tile][d][64]
      __syncthreads();
      #pragma unroll
      for (int mt = 0; mt < 4; ++mt)
        #pragma unroll
        for (int nt = 0; nt < 4; ++nt) {
          int dl = wn + nt * 16 + l16;
          int sl = wm + mt * 16 + quad * 4;
          int2 pk;
          pk.x = pkbf(acc[mt][nt][0], acc[mt][nt][1]);
          pk.y = pkbf(acc[mt][nt][2], acc[mt][nt][3]);
          *(int2*)&As[dl * 136 + sl] = pk;
        }
      __syncthreads();
      #pragma unroll
      for (int rd = 0; rd < 8; ++rd) {
        int dl = (tid >> 4) + rd * 16;           // d 0..127
        int sl = (tid & 15) * 8;                 // s_local 0..120 step 8
        int tile = (ss >> 6) + (sl >> 6);
        int tl = sl & 63;
        int ch = (tl >> 3) ^ (dl & 7);
        int4 vv = *(const int4*)&As[dl * 136 + sl];
        *(int4*)&Vg[(((size_t)(bb * NH + hh) * 32 + tile) * 128 + dl) * 64 + ch * 8] = vv;
      }
    }
  }
}

// ---------------- flash attention ----------------
// LDS 48 KB (K dbuf 32K + V single 16K) -> 3 blocks/CU (was 80K -> 2).
// P never touches LDS: quad redistribution in-register via
// permlane32_swap+permlane16_swap (reg<->lane-bit transposes).
// V race fix vs R1: V[jj] is produced and consumed in the SAME iteration,
// and vmcnt only tracks the issuing wave's DMAs while every wave reads the
// whole tile. So: each wave waits its OWN V group (counted vmcnt, K[jj+1]
// prefetch stays in flight), then a raw s_barrier => after the barrier all
// waves' V quarters are in LDS. Same pattern at iter top for K.
__global__ __launch_bounds__(256, 3) void k_attn(
    const short* __restrict__ Qg, const short* __restrict__ Kg,
    const short* __restrict__ Vt, short* __restrict__ Op,
    float* __restrict__ mlb) {
  __shared__ __attribute__((aligned(16))) short Ks[2][64 * 128];   // [s][d] swz, dbuf
  __shared__ __attribute__((aligned(16))) short Vs[64 * 128];      // [d][t] swz, single
  const int bid = blockIdx.x;
  const int bh = bid & 31, unit = bid >> 5;
  const int tid = threadIdx.x, wid = tid >> 6, lane = tid & 63;
  const int l16 = lane & 15, quad = lane >> 4, wq = wid * 32;
  const float CEXP2 = 23.083121f;       // 16 * log2(e)
  const short* Qp = Qg + (size_t)bh * S_LEN * DH;
  const short* Kp = Kg + (size_t)bh * S_LEN * DH;
  const short* Vb = Vt + (size_t)bh * 32 * 8192;   // [tile][d][64]
  int kcs[4], vcs[2];
  #pragma unroll
  for (int ks = 0; ks < 4; ++ks) kcs[ks] = ((ks * 4 + quad) ^ l16) * 8;
  #pragma unroll
  for (int ks = 0; ks < 2; ++ks) vcs[ks] = ((ks * 4 + quad) ^ (l16 & 7)) * 8;

  for (int seg = 0; seg < 2; ++seg) {
    const int qg = seg ? (15 - unit) : unit;
    const int par = seg;
    const int q0 = qg * 128, nj = qg + 1;
    __syncthreads();                    // Ks/Vs safe to overwrite (epilogue done)
    {                                   // prologue: K tile 0 only
      const short* kg = Kp + (size_t)(par * 64) * DH;
      #pragma unroll
      for (int i = 0; i < 4; ++i) {
        int sl = wid * 4 + i;
        gl2lds(kg + sl * 512 + lane * 8, &Ks[0][sl * 512]);
      }
    }
    bf16x8 qf[4][2];
    #pragma unroll
    for (int ks = 0; ks < 4; ++ks)
      #pragma unroll
      for (int qb = 0; qb < 2; ++qb)
        qf[ks][qb] = *(const bf16x8*)&Qp[(size_t)(q0 + wq + qb * 16 + l16) * DH +
                                         ks * 32 + quad * 8];
    float l_p[2] = {0.0f, 0.0f};
    f32x4 Oacc[8][2] = {};
    for (int jj = 0; jj < nj; ++jj) {
      const int b = jj & 1;
      const int j = par + 2 * jj;
      // iter-top: own K[jj] (and any older) retired, then all-wave barrier
      // => Ks[b] fully populated, Vs free to overwrite.
      asm volatile("s_waitcnt vmcnt(0)" ::: "memory");
      __builtin_amdgcn_s_barrier();
      __builtin_amdgcn_sched_barrier(0);
      {                                 // V[jj] into single buffer, issued early
        const short* vg = Vb + (size_t)j * 8192;
        #pragma unroll
        for (int i = 0; i < 4; ++i) {
          int sl = wid * 4 + i;
          gl2lds(vg + sl * 512 + lane * 8, &Vs[sl * 512]);
        }
      }
      const int havek = (jj + 1 < nj);
      if (havek) {                      // K[jj+1] prefetch (in flight past PV)
        const int jn = par + 2 * (jj + 1);
        const short* kg = Kp + (size_t)(jn * 64) * DH;
        #pragma unroll
        for (int i = 0; i < 4; ++i) {
          int sl = wid * 4 + i;
          gl2lds(kg + sl * 512 + lane * 8, &Ks[1 - b][sl * 512]);
        }
      }
      f32x4 Sc[4][2] = {};
      #pragma unroll
      for (int ks = 0; ks < 4; ++ks) {
        bf16x8 kfr[4];
        #pragma unroll
        for (int nt = 0; nt < 4; ++nt)
          kfr[nt] = *(const bf16x8*)&Ks[b][(nt * 16 + l16) * 128 + kcs[ks]];
        #pragma unroll
        for (int nt = 0; nt < 4; ++nt)
          #pragma unroll
          for (int qb = 0; qb < 2; ++qb)
            Sc[nt][qb] = __builtin_amdgcn_mfma_f32_16x16x32_bf16(kfr[nt], qf[ks][qb],
                                                                 Sc[nt][qb], 0, 0, 0);
      }
      if (jj == nj - 1) {
        #pragma unroll
        for (int nt = 0; nt < 4; ++nt)
          #pragma unroll
          for (int qb = 0; qb < 2; ++qb)
            #pragma unroll
            for (int r = 0; r < 4; ++r) {
              int tg = j * 64 + nt * 16 + quad * 4 + r;
              int qgl = q0 + wq + qb * 16 + l16;
              if (tg > qgl) Sc[nt][qb][r] = -1000.0f;  // exp2 -> 0
            }
      }
      // softmax + in-register P redistribution:
      // lane(quad qd) holds P[k=16nt+4qd+r][q=l16]; PV B-frag needs
      // P[k=32ks+8qd+0..7]. dest(qd,ks,w) <- src quad 2(qd&1)+(w>>1),
      // reg (nt=2ks+(qd>>1), half=w&1): one permlane32_swap (reg<->bit5)
      // + one permlane16_swap (reg<->bit4) per int pair.
      bf16x8 bpf[2][2];                 // [qb][ks]
      #pragma unroll
      for (int qb = 0; qb < 2; ++qb) {
        float ls0 = 0.0f, ls1 = 0.0f;
        #pragma unroll
        for (int nt = 0; nt < 4; ++nt)
          #pragma unroll
          for (int r = 0; r < 4; ++r) {
            float pe = __builtin_amdgcn_exp2f(Sc[nt][qb][r] - CEXP2);
            Sc[nt][qb][r] = pe;
            if (nt & 1) ls1 += pe; else ls0 += pe;
          }
        l_p[qb] += ls0 + ls1;
        int px[4], py[4];
        #pragma unroll
        for (int nt = 0; nt < 4; ++nt) {
          px[nt] = pkbf(Sc[nt][qb][0], Sc[nt][qb][1]);  // k=16nt+4qd+{0,1}
          py[nt] = pkbf(Sc[nt][qb][2], Sc[nt][qb][3]);  // k=16nt+4qd+{2,3}
        }
        pl32swap(px[0], px[1]); pl16swap(px[0], px[1]); // -> w0,w2 of ks=0
        pl32swap(py[0], py[1]); pl16swap(py[0], py[1]); // -> w1,w3 of ks=0
        pl32swap(px[2], px[3]); pl16swap(px[2], px[3]); // -> w0,w2 of ks=1
        pl32swap(py[2], py[3]); pl16swap(py[2], py[3]); // -> w1,w3 of ks=1
        union { int i[4]; bf16x8 v; } u0, u1;
        u0.i[0] = px[0]; u0.i[1] = py[0]; u0.i[2] = px[1]; u0.i[3] = py[1];
        u1.i[0] = px[2]; u1.i[1] = py[2]; u1.i[2] = px[3]; u1.i[3] = py[3];
        bpf[qb][0] = u0.v; bpf[qb][1] = u1.v;
      }
      // V-ready handshake: own V group retired (vmcnt counts per-wave,
      // in-order: 4 V then 4 K outstanding => vmcnt(4) retires V), then
      // raw barrier => ALL waves' V quarters landed. K prefetch in flight.
      if (havek) asm volatile("s_waitcnt vmcnt(4)" ::: "memory");
      else       asm volatile("s_waitcnt vmcnt(0)" ::: "memory");
      __builtin_amdgcn_s_barrier();
      __builtin_amdgcn_sched_barrier(0);
      #pragma unroll
      for (int ks = 0; ks < 2; ++ks) {
        bf16x8 vfr[8];
        #pragma unroll
        for (int nt = 0; nt < 8; ++nt)
          vfr[nt] = *(const bf16x8*)&Vs[(nt * 16 + l16) * 64 + vcs[ks]];
        #pragma unroll
        for (int nt = 0; nt < 8; ++nt)
          #pragma unroll
          for (int qb = 0; qb < 2; ++qb)
            Oacc[nt][qb] = __builtin_amdgcn_mfma_f32_16x16x32_bf16(vfr[nt], bpf[qb][ks],
                                                                   Oacc[nt][qb], 0, 0, 0);
      }
    }
    __syncthreads();
    short* osl = &Ks[0][0] + wid * 4096;     // 32 q x 128 d per wave (spans Ks dbuf)
    #pragma unroll
    for (int qb = 0; qb < 2; ++qb)
      #pragma unroll
      for (int nt = 0; nt < 8; ++nt) {
        int2 ov;
        ov.x = pkbf(Oacc[nt][qb][0], Oacc[nt][qb][1]);
        ov.y = pkbf(Oacc[nt][qb][2], Oacc[nt][qb][3]);
        int ch = ((nt * 2 + (quad >> 1)) ^ l16) * 8 + (quad & 1) * 4;
        *(int2*)&osl[(qb * 16 + l16) * 128 + ch] = ov;
      }
    size_t obase = ((size_t)(par * 32 + bh) * S_LEN + q0 + wq) * DH;
    #pragma unroll
    for (int it = 0; it < 8; ++it) {
      int u = lane + 64 * it;
      int row = u >> 4, c = u & 15;
      *(int4*)&Op[obase + (size_t)row * DH + c * 8] =
          *(const int4*)&osl[row * 128 + ((c ^ (row & 15)) * 8)];
    }
    #pragma unroll
    for (int qb = 0; qb < 2; ++qb) {
      float lt = l_p[qb];
      lt += __shfl_xor(lt, 16);
      lt += __shfl_xor(lt, 32);
      int qrow = q0 + wq + qb * 16 + l16;
      if (quad == 0)
        mlb[(size_t)(par * 32 + bh) * S_LEN + qrow] = lt;
    }
  }
}

// ---------------- output projection with parity merge ----------------
// grid (128 m-tiles of 32, splitK 4) = 512 blocks = 2/CU; k-chunks of 128
// (one head per round); merge = (O1+O2)*1/(l1+l2); atomicAdd into zeroed out.
__global__ __launch_bounds__(256, 2) void k_out(
    const short* __restrict__ Op, const float* __restrict__ mlb,
    const short* __restrict__ WoT, float* __restrict__ out) {
  __shared__ __attribute__((aligned(16))) short As[32 * 136];
  __shared__ __attribute__((aligned(16))) short Bs[128 * 136];
  __shared__ float cw[4][32];
  const int m0 = blockIdx.x * 32, h0 = blockIdx.y * 4;
  const int tid = threadIdx.x, wid = tid >> 6, lane = tid & 63;
  const int l16 = lane & 15, quad = lane >> 4;
  const int wm = (wid & 1) * 16, wn = (wid >> 1) * 64;
  if (tid < 128) {
    int rr = tid & 31, hh = tid >> 5;
    int row = m0 + rr, b = row >> 11, s = row & 2047;
    int bh = b * NH + h0 + hh;
    float l1 = mlb[(size_t)bh * S_LEN + s];
    float l2 = mlb[(size_t)(32 + bh) * S_LEN + s];
    cw[hh][rr] = 1.0f / (l1 + l2);
  }
  __syncthreads();
  f32x4 acc[4] = {};
  for (int hc = 0; hc < 4; ++hc) {
    int h = h0 + hc;
    #pragma unroll
    for (int it = 0; it < 4; ++it) {
      int e = tid + 256 * it;                  // 1024 short4-units = 32m x 128d
      int rr = e >> 5, c4 = (e & 31) * 4;
      int row = m0 + rr, b = row >> 11, s = row & 2047;
      size_t base = ((size_t)(b * NH + h) * S_LEN + s) * DH + c4;
      short4 u1 = *(const short4*)&Op[base];
      short4 u2 = *(const short4*)&Op[(size_t)32 * S_LEN * DH + base];
      float c1 = cw[hc][rr];
      int2 o;
      o.x = pkbf(c1 * (bf2f(u1.x) + bf2f(u2.x)), c1 * (bf2f(u1.y) + bf2f(u2.y)));
      o.y = pkbf(c1 * (bf2f(u1.z) + bf2f(u2.z)), c1 * (bf2f(u1.w) + bf2f(u2.w)));
      *(int2*)&As[rr * 136 + c4] = o;
    }
    for (int e = tid; e < 2048; e += 256)
      *(int4*)&Bs[(e >> 4) * 136 + (e & 15) * 8] =
          *(const int4*)&WoT[(size_t)(e >> 4) * INNER + h * 128 + (e & 15) * 8];
    __syncthreads();
    #pragma unroll
    for (int ks = 0; ks < 4; ++ks) {
      bf16x8 a = *(const bf16x8*)&As[(wm + l16) * 136 + ks * 32 + quad * 8];
      bf16x8 b[4];
      #pragma unroll
      for (int nt = 0; nt < 4; ++nt)
        b[nt] = *(const bf16x8*)&Bs[(wn + nt * 16 + l16) * 136 + ks * 32 + quad * 8];
      #pragma unroll
      for (int nt = 0; nt < 4; ++nt)
        acc[nt] = __builtin_amdgcn_mfma_f32_16x16x32_bf16(a, b[nt], acc[nt], 0, 0, 0);
    }
    __syncthreads();
  }
  #pragma unroll
  for (int nt = 0; nt < 4; ++nt)
    #pragma unroll
    for (int r = 0; r < 4; ++r) {
      int gm = m0 + wm + quad * 4 + r;
      int gn = wn + nt * 16 + l16;
      atomicAdd(&out[(size_t)gm * 128 + gn], acc[nt][r]);
    }
}

// ---------------- launch ----------------
extern "C" void kernel_launch(void* const* d_in, const int* in_sizes, int n_in,
                              void* d_out, int out_size, void* d_ws, size_t ws_size,
                              hipStream_t stream) {
  const float* q  = (const float*)d_in[0];
  const float* Wq = (const float*)d_in[1];
  const float* Wk = (const float*)d_in[2];
  const float* Wv = (const float*)d_in[3];
  const float* Wo = (const float*)d_in[4];
  float* out = (float*)d_out;
  char* ws = (char*)d_ws;
  const size_t MB = 1024 * 1024;
  float* csT = (float*)(ws + 0);                   // 1 MB   [s][i]{cos,sin}
  short* WT  = (short*)(ws + 1 * MB);              // 1.5 MB
  short* WoT = (short*)(ws + 2 * MB + 512 * 1024); // 512 KB
  short* Xbf = (short*)(ws + 3 * MB);              // 2 MB
  short* Qg  = (short*)(ws + 8 * MB);              // 16 MB  [bh][s][d]
  short* Kg  = (short*)(ws + 24 * MB);             // 16 MB  [bh][s][d] swz
  short* Vg  = (short*)(ws + 40 * MB);             // 16 MB  [bh][tile][d][64] swz
  short* Op  = (short*)(ws + 56 * MB);             // 32 MB  [par][bh][s][d]
  float* mlb = (float*)(ws + 88 * MB);             // 512 KB [par][bh][s]

  k_prep<<<2304, 256, 0, stream>>>(q, Wq, Wk, Wv, Wo, csT, Xbf, WT, WoT, out);
  k_qkv<<<dim3(16, 32), 256, 0, stream>>>(Xbf, WT, csT, Qg, Kg, Vg);
  k_attn<<<512, 256, 0, stream>>>(Qg, Kg, Vg, Op, mlb);
  k_out<<<dim3(128, 4), 256, 0, stream>>>(Op, mlb, WoT, out);
}

// Round 3
// 151.560 us; speedup vs baseline: 1.1155x; 1.1155x over previous
//
#include <hip/hip_runtime.h>
#include <math.h>

#define S_LEN 2048
#define NH 16
#define DH 128
#define INNER 2048   // NH*DH
#define NROWS 4096   // B*S

typedef __attribute__((ext_vector_type(8))) short bf16x8;
typedef __attribute__((ext_vector_type(4))) float f32x4;
typedef __attribute__((ext_vector_type(2))) unsigned int u32x2;

__device__ __forceinline__ short f2bf(float f) {
  union { float f; unsigned u; } v; v.f = f;
  unsigned r = (v.u + 0x7fffu + ((v.u >> 16) & 1u)) >> 16;
  return (short)(unsigned short)r;
}
__device__ __forceinline__ float bf2f(short s) {
  union { unsigned u; float f; } v; v.u = ((unsigned)(unsigned short)s) << 16;
  return v.f;
}
// pack two f32 -> two bf16 in one uint: 2 adds + 1 v_perm (round half-away)
__device__ __forceinline__ int pkbf(float lo, float hi) {
  union { float f; unsigned u; } x, y;
  x.f = lo; y.f = hi;
  return (int)__builtin_amdgcn_perm(y.u + 0x8000u, x.u + 0x8000u, 0x07060302u);
}
// async global->LDS DMA, 16B per lane; LDS dest = uniform base + lane*16
__device__ __forceinline__ void gl2lds(const short* g, short* l) {
  __builtin_amdgcn_global_load_lds(
      (const __attribute__((address_space(1))) unsigned int*)g,
      (__attribute__((address_space(3))) unsigned int*)l, 16, 0, 0);
}
// (reg <-> lane-bit5) transpose: a' = {a lo32, b lo32}, b' = {a hi32, b hi32}
__device__ __forceinline__ void pl32swap(int& a, int& b) {
  u32x2 r = __builtin_amdgcn_permlane32_swap((unsigned)a, (unsigned)b, false, false);
  a = (int)r.x; b = (int)r.y;
}
// (reg <-> lane-bit4) transpose
__device__ __forceinline__ void pl16swap(int& a, int& b) {
  u32x2 r = __builtin_amdgcn_permlane16_swap((unsigned)a, (unsigned)b, false, false);
  a = (int)r.x; b = (int)r.y;
}

// ---------------- fused prep ----------------
// grid 2304: [0,512) rope table csT[s][i]{cos,sin}; [512,1024) X fp32->bf16;
// [1024,1792) Wq/Wk/Wv transpose; [1792,2048) Wo transpose; [2048,2304) zero out
__global__ void k_prep(const float* __restrict__ X, const float* __restrict__ Wq,
                       const float* __restrict__ Wk, const float* __restrict__ Wv,
                       const float* __restrict__ Wo,
                       float* __restrict__ csT, short* __restrict__ Xbf,
                       short* __restrict__ WT, short* __restrict__ WoT,
                       float* __restrict__ outz) {
  const int bx = blockIdx.x, tid = threadIdx.x;
  if (bx < 512) {
    int idx = bx * 256 + tid;           // s*64 + i
    int i = idx & 63, s = idx >> 6;
    double invf = pow(10000.0, -(double)i / 64.0);
    float ang = (float)((double)s * invf);
    float sv, cv; sincosf(ang, &sv, &cv);
    csT[idx * 2] = cv; csT[idx * 2 + 1] = sv;
    return;
  }
  if (bx < 1024) {
    int idx = ((bx - 512) * 256 + tid) * 4;
    float4 xv = *(const float4*)&X[idx];
    short4 o; o.x = f2bf(xv.x); o.y = f2bf(xv.y); o.z = f2bf(xv.z); o.w = f2bf(xv.w);
    *(short4*)&Xbf[idx] = o;
    return;
  }
  if (bx >= 2048) {                     // zero d_out
    float4 z4 = make_float4(0.f, 0.f, 0.f, 0.f);
    ((float4*)outz)[(bx - 2048) * 512 + tid] = z4;
    ((float4*)outz)[(bx - 2048) * 512 + tid + 256] = z4;
    return;
  }
  __shared__ float tile[32][33];
  const float* src; short* dst; int R, C, c0, r0;
  if (bx < 1792) {
    int z = (bx - 1024) >> 8, t = (bx - 1024) & 255;
    src = (z == 0) ? Wq : ((z == 1) ? Wk : Wv);
    dst = WT + (size_t)z * INNER * 128; R = 128; C = INNER;
    c0 = (t & 63) * 32; r0 = (t >> 6) * 32;
  } else {
    int t = bx - 1792;
    src = Wo; dst = WoT; R = INNER; C = 128;
    c0 = (t & 3) * 32; r0 = (t >> 2) * 32;
  }
  int tx = tid & 31, ty = tid >> 5;     // 32 x 8
  #pragma unroll
  for (int dy = 0; dy < 32; dy += 8)
    tile[ty + dy][tx] = src[(size_t)(r0 + ty + dy) * C + c0 + tx];
  __syncthreads();
  #pragma unroll
  for (int dy = 0; dy < 32; dy += 8)
    dst[(size_t)(c0 + ty + dy) * R + r0 + tx] = f2bf(tile[tx][ty + dy]);
}

// ---------------- fused QKV projection + RoPE ----------------
// grid (16 n-tiles = one head, 32 m-tiles of 128). Q/K MFMA transposed
// (rows = d): RoPE pairs in-lane, packed b64 epilogue. Q carries
// qscale*log2(e) so attention scores emerge in log2 domain.
// Q [bh][s][d] plain; K [bh][s][d] chunk-XOR swz; V [bh][tile][d][64] swz.
__global__ __launch_bounds__(256, 2) void k_qkv(
    const short* __restrict__ Xbf, const short* __restrict__ WT,
    const float* __restrict__ csT,
    short* __restrict__ Qg, short* __restrict__ Kg, short* __restrict__ Vg) {
  __shared__ __attribute__((aligned(16))) short As[128 * 136];
  __shared__ __attribute__((aligned(16))) short Bs[128 * 136];
  const int tid = threadIdx.x;
  const int n0 = blockIdx.x * 128, m0 = blockIdx.y * 128;
  for (int e = tid; e < 2048; e += 256)
    *(int4*)&As[(e >> 4) * 136 + (e & 15) * 8] =
        *(const int4*)&Xbf[(size_t)(m0 + (e >> 4)) * 128 + (e & 15) * 8];
  const int wid = tid >> 6, lane = tid & 63;
  const int l16 = lane & 15, quad = lane >> 4;
  const int wm = (wid & 1) * 64, wn = (wid >> 1) * 64;
  const int hh = n0 >> 7;                       // this block's head
  const int bb = m0 >> 11, ss = m0 & 2047;      // batch, seq base
  const float qscale = 0.12751745f;             // (1/sqrt(128)) * log2(e)
  for (int z = 0; z < 3; ++z) {
    __syncthreads();
    const short* Wp = WT + (size_t)z * INNER * 128;
    for (int e = tid; e < 2048; e += 256)
      *(int4*)&Bs[(e >> 4) * 136 + (e & 15) * 8] =
          *(const int4*)&Wp[(size_t)(n0 + (e >> 4)) * 128 + (e & 15) * 8];
    __syncthreads();
    f32x4 acc[4][4] = {};
    #pragma unroll
    for (int ks = 0; ks < 4; ++ks) {
      bf16x8 ax[4], bw[4];
      #pragma unroll
      for (int j = 0; j < 4; ++j) {
        ax[j] = *(const bf16x8*)&As[(wm + j * 16 + l16) * 136 + ks * 32 + quad * 8];
        bw[j] = *(const bf16x8*)&Bs[(wn + j * 16 + l16) * 136 + ks * 32 + quad * 8];
      }
      if (z < 2) {   // D[d][s]: A = W (m=d), B = X (n=s)
        #pragma unroll
        for (int dt = 0; dt < 4; ++dt)
          #pragma unroll
          for (int st = 0; st < 4; ++st)
            acc[dt][st] = __builtin_amdgcn_mfma_f32_16x16x32_bf16(bw[dt], ax[st], acc[dt][st], 0, 0, 0);
      } else {       // D[s][d]: A = X (m=s), B = W (n=d)
        #pragma unroll
        for (int mt = 0; mt < 4; ++mt)
          #pragma unroll
          for (int nt = 0; nt < 4; ++nt)
            acc[mt][nt] = __builtin_amdgcn_mfma_f32_16x16x32_bf16(ax[mt], bw[nt], acc[mt][nt], 0, 0, 0);
      }
    }
    if (z < 2) {
      __syncthreads();                  // waves done reading Bs
      #pragma unroll
      for (int dt = 0; dt < 4; ++dt)
        #pragma unroll
        for (int st = 0; st < 4; ++st) {
          int d0 = wn + dt * 16 + quad * 4;     // multiple of 4
          int sl = wm + st * 16 + l16;
          int sg = ss + sl;
          float4 cs = *(const float4*)&csT[((size_t)sg * 64 + (d0 >> 1)) * 2];
          float x0 = acc[dt][st][0], x1 = acc[dt][st][1];
          float x2 = acc[dt][st][2], x3 = acc[dt][st][3];
          float r0 = x0 * cs.x - x1 * cs.y, r1 = x1 * cs.x + x0 * cs.y;
          float r2 = x2 * cs.z - x3 * cs.w, r3 = x3 * cs.z + x2 * cs.w;
          if (z == 0) { r0 *= qscale; r1 *= qscale; r2 *= qscale; r3 *= qscale; }
          int2 pk; pk.x = pkbf(r0, r1); pk.y = pkbf(r2, r3);
          *(int2*)&Bs[sl * 136 + d0] = pk;
        }
      __syncthreads();
      short* dst = (z == 0 ? Qg : Kg) + (((size_t)(bb * NH + hh)) * S_LEN + ss) * DH;
      #pragma unroll
      for (int it = 0; it < 8; ++it) {
        int u = tid + 256 * it;                   // 2048 int4 units
        int row = u >> 4, c = u & 15;
        int cc = (z == 0) ? c : (c ^ (row & 15)); // K: chunk swizzle
        *(int4*)&dst[(size_t)row * DH + cc * 8] = *(const int4*)&Bs[row * 136 + c * 8];
      }
    } else {
      // V: transpose through As (dead now), tiled+swizzled [bh][tile][d][64]
      __syncthreads();
      #pragma unroll
      for (int mt = 0; mt < 4; ++mt)
        #pragma unroll
        for (int nt = 0; nt < 4; ++nt) {
          int dl = wn + nt * 16 + l16;
          int sl = wm + mt * 16 + quad * 4;
          int2 pk;
          pk.x = pkbf(acc[mt][nt][0], acc[mt][nt][1]);
          pk.y = pkbf(acc[mt][nt][2], acc[mt][nt][3]);
          *(int2*)&As[dl * 136 + sl] = pk;
        }
      __syncthreads();
      #pragma unroll
      for (int rd = 0; rd < 8; ++rd) {
        int dl = (tid >> 4) + rd * 16;           // d 0..127
        int sl = (tid & 15) * 8;                 // s_local 0..120 step 8
        int tile = (ss >> 6) + (sl >> 6);
        int tl = sl & 63;
        int ch = (tl >> 3) ^ (dl & 7);
        int4 vv = *(const int4*)&As[dl * 136 + sl];
        *(int4*)&Vg[(((size_t)(bb * NH + hh) * 32 + tile) * 128 + dl) * 64 + ch * 8] = vv;
      }
    }
  }
}

// ---------------- flash attention ----------------
// R3 = R0's proven schedule (K AND V double-buffered, depth-1 prefetch,
// ONE __syncthreads per iteration -- its implicit vmcnt(0) drain is exactly
// the wait for the prefetch issued one full iteration earlier) + permlane
// in-register P redistribution (Ps LDS buffer deleted; 80->64 KB) +
// s_setprio around MFMA clusters (T5).
__global__ __launch_bounds__(256, 2) void k_attn(
    const short* __restrict__ Qg, const short* __restrict__ Kg,
    const short* __restrict__ Vt, short* __restrict__ Op,
    float* __restrict__ mlb) {
  __shared__ __attribute__((aligned(16))) short Ks[2][64 * 128];   // [s][d] swz
  __shared__ __attribute__((aligned(16))) short Vs[2][128 * 64];   // [d][t] swz
  const int bid = blockIdx.x;
  const int bh = bid & 31, unit = bid >> 5;
  const int tid = threadIdx.x, wid = tid >> 6, lane = tid & 63;
  const int l16 = lane & 15, quad = lane >> 4, wq = wid * 32;
  const float CEXP2 = 23.083121f;       // 16 * log2(e)
  const short* Qp = Qg + (size_t)bh * S_LEN * DH;
  const short* Kp = Kg + (size_t)bh * S_LEN * DH;
  const short* Vb = Vt + (size_t)bh * 32 * 8192;   // [tile][d][64]
  int kcs[4], vcs[2];
  #pragma unroll
  for (int ks = 0; ks < 4; ++ks) kcs[ks] = ((ks * 4 + quad) ^ l16) * 8;
  #pragma unroll
  for (int ks = 0; ks < 2; ++ks) vcs[ks] = ((ks * 4 + quad) ^ (l16 & 7)) * 8;

  for (int seg = 0; seg < 2; ++seg) {
    const int qg = seg ? (15 - unit) : unit;
    const int par = seg;
    const int q0 = qg * 128, nj = qg + 1;
    __syncthreads();                    // Ks/Vs safe to overwrite (epilogue done)
    {                                   // prologue: K/V tile 0
      const short* kg = Kp + (size_t)(par * 64) * DH;
      const short* vg = Vb + (size_t)par * 8192;
      #pragma unroll
      for (int i = 0; i < 4; ++i) {
        int sl = wid * 4 + i;
        gl2lds(kg + sl * 512 + lane * 8, &Ks[0][sl * 512]);
        gl2lds(vg + sl * 512 + lane * 8, &Vs[0][sl * 512]);
      }
    }
    bf16x8 qf[4][2];
    #pragma unroll
    for (int ks = 0; ks < 4; ++ks)
      #pragma unroll
      for (int qb = 0; qb < 2; ++qb)
        qf[ks][qb] = *(const bf16x8*)&Qp[(size_t)(q0 + wq + qb * 16 + l16) * DH +
                                         ks * 32 + quad * 8];
    float l_p[2] = {0.0f, 0.0f};
    f32x4 Oacc[8][2] = {};
    for (int jj = 0; jj < nj; ++jj) {
      const int b = jj & 1;
      const int j = par + 2 * jj;
      __syncthreads();                  // drains K/V[jj] DMA (issued iter jj-1)
      if (jj + 1 < nj) {                // depth-1 prefetch: full-iter window
        const int jn = par + 2 * (jj + 1);
        const short* kg = Kp + (size_t)(jn * 64) * DH;
        const short* vg = Vb + (size_t)jn * 8192;
        #pragma unroll
        for (int i = 0; i < 4; ++i) {
          int sl = wid * 4 + i;
          gl2lds(kg + sl * 512 + lane * 8, &Ks[1 - b][sl * 512]);
          gl2lds(vg + sl * 512 + lane * 8, &Vs[1 - b][sl * 512]);
        }
      }
      f32x4 Sc[4][2] = {};
      #pragma unroll
      for (int ks = 0; ks < 4; ++ks) {
        bf16x8 kfr[4];
        #pragma unroll
        for (int nt = 0; nt < 4; ++nt)
          kfr[nt] = *(const bf16x8*)&Ks[b][(nt * 16 + l16) * 128 + kcs[ks]];
        __builtin_amdgcn_s_setprio(1);
        #pragma unroll
        for (int nt = 0; nt < 4; ++nt)
          #pragma unroll
          for (int qb = 0; qb < 2; ++qb)
            Sc[nt][qb] = __builtin_amdgcn_mfma_f32_16x16x32_bf16(kfr[nt], qf[ks][qb],
                                                                 Sc[nt][qb], 0, 0, 0);
        __builtin_amdgcn_s_setprio(0);
      }
      if (jj == nj - 1) {
        #pragma unroll
        for (int nt = 0; nt < 4; ++nt)
          #pragma unroll
          for (int qb = 0; qb < 2; ++qb)
            #pragma unroll
            for (int r = 0; r < 4; ++r) {
              int tg = j * 64 + nt * 16 + quad * 4 + r;
              int qgl = q0 + wq + qb * 16 + l16;
              if (tg > qgl) Sc[nt][qb][r] = -1000.0f;  // exp2 -> 0
            }
      }
      // softmax + in-register P redistribution:
      // lane(quad qd) holds P[k=16nt+4qd+r][q=l16]; PV B-frag needs
      // P[k=32ks+8qd+0..7]. dest(qd,ks,w) <- src quad 2(qd&1)+(w>>1),
      // reg (nt=2ks+(qd>>1), half=w&1): one permlane32_swap (reg<->bit5)
      // + one permlane16_swap (reg<->bit4) per int pair.
      bf16x8 bpf[2][2];                 // [qb][ks]
      #pragma unroll
      for (int qb = 0; qb < 2; ++qb) {
        float ls0 = 0.0f, ls1 = 0.0f;
        #pragma unroll
        for (int nt = 0; nt < 4; ++nt)
          #pragma unroll
          for (int r = 0; r < 4; ++r) {
            float pe = __builtin_amdgcn_exp2f(Sc[nt][qb][r] - CEXP2);
            Sc[nt][qb][r] = pe;
            if (nt & 1) ls1 += pe; else ls0 += pe;
          }
        l_p[qb] += ls0 + ls1;
        int px[4], py[4];
        #pragma unroll
        for (int nt = 0; nt < 4; ++nt) {
          px[nt] = pkbf(Sc[nt][qb][0], Sc[nt][qb][1]);  // k=16nt+4qd+{0,1}
          py[nt] = pkbf(Sc[nt][qb][2], Sc[nt][qb][3]);  // k=16nt+4qd+{2,3}
        }
        pl32swap(px[0], px[1]); pl16swap(px[0], px[1]); // -> w0,w2 of ks=0
        pl32swap(py[0], py[1]); pl16swap(py[0], py[1]); // -> w1,w3 of ks=0
        pl32swap(px[2], px[3]); pl16swap(px[2], px[3]); // -> w0,w2 of ks=1
        pl32swap(py[2], py[3]); pl16swap(py[2], py[3]); // -> w1,w3 of ks=1
        union { int i[4]; bf16x8 v; } u0, u1;
        u0.i[0] = px[0]; u0.i[1] = py[0]; u0.i[2] = px[1]; u0.i[3] = py[1];
        u1.i[0] = px[2]; u1.i[1] = py[2]; u1.i[2] = px[3]; u1.i[3] = py[3];
        bpf[qb][0] = u0.v; bpf[qb][1] = u1.v;
      }
      #pragma unroll
      for (int ks = 0; ks < 2; ++ks) {
        bf16x8 vfr[8];
        #pragma unroll
        for (int nt = 0; nt < 8; ++nt)
          vfr[nt] = *(const bf16x8*)&Vs[b][(nt * 16 + l16) * 64 + vcs[ks]];
        __builtin_amdgcn_s_setprio(1);
        #pragma unroll
        for (int nt = 0; nt < 8; ++nt)
          #pragma unroll
          for (int qb = 0; qb < 2; ++qb)
            Oacc[nt][qb] = __builtin_amdgcn_mfma_f32_16x16x32_bf16(vfr[nt], bpf[qb][ks],
                                                                   Oacc[nt][qb], 0, 0, 0);
        __builtin_amdgcn_s_setprio(0);
      }
    }
    __syncthreads();
    short* osl = &Ks[0][0] + wid * 4096;     // 32 q x 128 d per wave (spans Ks dbuf)
    #pragma unroll
    for (int qb = 0; qb < 2; ++qb)
      #pragma unroll
      for (int nt = 0; nt < 8; ++nt) {
        int2 ov;
        ov.x = pkbf(Oacc[nt][qb][0], Oacc[nt][qb][1]);
        ov.y = pkbf(Oacc[nt][qb][2], Oacc[nt][qb][3]);
        int ch = ((nt * 2 + (quad >> 1)) ^ l16) * 8 + (quad & 1) * 4;
        *(int2*)&osl[(qb * 16 + l16) * 128 + ch] = ov;
      }
    size_t obase = ((size_t)(par * 32 + bh) * S_LEN + q0 + wq) * DH;
    #pragma unroll
    for (int it = 0; it < 8; ++it) {
      int u = lane + 64 * it;
      int row = u >> 4, c = u & 15;
      *(int4*)&Op[obase + (size_t)row * DH + c * 8] =
          *(const int4*)&osl[row * 128 + ((c ^ (row & 15)) * 8)];
    }
    #pragma unroll
    for (int qb = 0; qb < 2; ++qb) {
      float lt = l_p[qb];
      lt += __shfl_xor(lt, 16);
      lt += __shfl_xor(lt, 32);
      int qrow = q0 + wq + qb * 16 + l16;
      if (quad == 0)
        mlb[(size_t)(par * 32 + bh) * S_LEN + qrow] = lt;
    }
  }
}

// ---------------- output projection with parity merge ----------------
// grid (128 m-tiles of 32, splitK 4) = 512 blocks = 2/CU; k-chunks of 128
// (one head per round); merge = (O1+O2)*1/(l1+l2); atomicAdd into zeroed out.
__global__ __launch_bounds__(256, 2) void k_out(
    const short* __restrict__ Op, const float* __restrict__ mlb,
    const short* __restrict__ WoT, float* __restrict__ out) {
  __shared__ __attribute__((aligned(16))) short As[32 * 136];
  __shared__ __attribute__((aligned(16))) short Bs[128 * 136];
  __shared__ float cw[4][32];
  const int m0 = blockIdx.x * 32, h0 = blockIdx.y * 4;
  const int tid = threadIdx.x, wid = tid >> 6, lane = tid & 63;
  const int l16 = lane & 15, quad = lane >> 4;
  const int wm = (wid & 1) * 16, wn = (wid >> 1) * 64;
  if (tid < 128) {
    int rr = tid & 31, hh = tid >> 5;
    int row = m0 + rr, b = row >> 11, s = row & 2047;
    int bh = b * NH + h0 + hh;
    float l1 = mlb[(size_t)bh * S_LEN + s];
    float l2 = mlb[(size_t)(32 + bh) * S_LEN + s];
    cw[hh][rr] = 1.0f / (l1 + l2);
  }
  __syncthreads();
  f32x4 acc[4] = {};
  for (int hc = 0; hc < 4; ++hc) {
    int h = h0 + hc;
    #pragma unroll
    for (int it = 0; it < 4; ++it) {
      int e = tid + 256 * it;                  // 1024 short4-units = 32m x 128d
      int rr = e >> 5, c4 = (e & 31) * 4;
      int row = m0 + rr, b = row >> 11, s = row & 2047;
      size_t base = ((size_t)(b * NH + h) * S_LEN + s) * DH + c4;
      short4 u1 = *(const short4*)&Op[base];
      short4 u2 = *(const short4*)&Op[(size_t)32 * S_LEN * DH + base];
      float c1 = cw[hc][rr];
      int2 o;
      o.x = pkbf(c1 * (bf2f(u1.x) + bf2f(u2.x)), c1 * (bf2f(u1.y) + bf2f(u2.y)));
      o.y = pkbf(c1 * (bf2f(u1.z) + bf2f(u2.z)), c1 * (bf2f(u1.w) + bf2f(u2.w)));
      *(int2*)&As[rr * 136 + c4] = o;
    }
    for (int e = tid; e < 2048; e += 256)
      *(int4*)&Bs[(e >> 4) * 136 + (e & 15) * 8] =
          *(const int4*)&WoT[(size_t)(e >> 4) * INNER + h * 128 + (e & 15) * 8];
    __syncthreads();
    #pragma unroll
    for (int ks = 0; ks < 4; ++ks) {
      bf16x8 a = *(const bf16x8*)&As[(wm + l16) * 136 + ks * 32 + quad * 8];
      bf16x8 b[4];
      #pragma unroll
      for (int nt = 0; nt < 4; ++nt)
        b[nt] = *(const bf16x8*)&Bs[(wn + nt * 16 + l16) * 136 + ks * 32 + quad * 8];
      #pragma unroll
      for (int nt = 0; nt < 4; ++nt)
        acc[nt] = __builtin_amdgcn_mfma_f32_16x16x32_bf16(a, b[nt], acc[nt], 0, 0, 0);
    }
    __syncthreads();
  }
  #pragma unroll
  for (int nt = 0; nt < 4; ++nt)
    #pragma unroll
    for (int r = 0; r < 4; ++r) {
      int gm = m0 + wm + quad * 4 + r;
      int gn = wn + nt * 16 + l16;
      atomicAdd(&out[(size_t)gm * 128 + gn], acc[nt][r]);
    }
}

// ---------------- launch ----------------
extern "C" void kernel_launch(void* const* d_in, const int* in_sizes, int n_in,
                              void* d_out, int out_size, void* d_ws, size_t ws_size,
                              hipStream_t stream) {
  const float* q  = (const float*)d_in[0];
  const float* Wq = (const float*)d_in[1];
  const float* Wk = (const float*)d_in[2];
  const float* Wv = (const float*)d_in[3];
  const float* Wo = (const float*)d_in[4];
  float* out = (float*)d_out;
  char* ws = (char*)d_ws;
  const size_t MB = 1024 * 1024;
  float* csT = (float*)(ws + 0);                   // 1 MB   [s][i]{cos,sin}
  short* WT  = (short*)(ws + 1 * MB);              // 1.5 MB
  short* WoT = (short*)(ws + 2 * MB + 512 * 1024); // 512 KB
  short* Xbf = (short*)(ws + 3 * MB);              // 2 MB
  short* Qg  = (short*)(ws + 8 * MB);              // 16 MB  [bh][s][d]
  short* Kg  = (short*)(ws + 24 * MB);             // 16 MB  [bh][s][d] swz
  short* Vg  = (short*)(ws + 40 * MB);             // 16 MB  [bh][tile][d][64] swz
  short* Op  = (short*)(ws + 56 * MB);             // 32 MB  [par][bh][s][d]
  float* mlb = (float*)(ws + 88 * MB);             // 512 KB [par][bh][s]

  k_prep<<<2304, 256, 0, stream>>>(q, Wq, Wk, Wv, Wo, csT, Xbf, WT, WoT, out);
  k_qkv<<<dim3(16, 32), 256, 0, stream>>>(Xbf, WT, csT, Qg, Kg, Vg);
  k_attn<<<512, 256, 0, stream>>>(Qg, Kg, Vg, Op, mlb);
  k_out<<<dim3(128, 4), 256, 0, stream>>>(Op, mlb, WoT, out);
}